// Round 13
// baseline (113.395 us; speedup 1.0000x reference)
//
#include <hip/hip_runtime.h>
#include <stdint.h>

// out[b,i,s] = (||w_i||^2 - 2*sum_o w[i,o]x[b,o,s] + ||x_{b,:,s}||^2) / K
// B=4, M=4096, K=1024, N=2048 (flattened N'=8192). fp32 in/out.
// MX-fp8 cross term (mfma_scale 16x16x128, unit scales); w2/x2 exact fp32.
// R13: NO-LDS GEMM. Operands are 12 MB fp8 (L2-fits) -> LDS staging was the
// bottleneck (96KB/blk-iter through the LDS pipe). Preps emit FRAG-LINEAR
// tiles: subtile (16 rows x 128 k-bytes) stored so lane l's frag bytes are
// at l*32 -> every frag is one contiguous 2KB wave read from L2. GEMM has
// no LDS, no barriers: independent waves + register ping-pong.

#define M_DIM 4096
#define K_DIM 1024
#define N_DIM 2048
#define B_DIM 4
#define NF 8192  // flattened B*N

#define BM 128
#define BN 128
#define NKT 8           // K tiles of 128 bytes
#define MT (M_DIM / BM) // 32
#define NT (NF / BN)    // 64
#define NBLK (MT * NT)  // 2048
#define STRIP 16384     // bytes per 16-row strip: 8 subtiles x 2KB

typedef __attribute__((ext_vector_type(4))) int i32x4;
typedef __attribute__((ext_vector_type(8))) int i32x8;
typedef __attribute__((ext_vector_type(4))) float f32x4;
typedef __attribute__((ext_vector_type(4))) float f32x4v;

// tiled address for (row r, k-byte k) in a frag-linear matrix:
// strip r>>4, subtile k>>7, then g=(k&127)>>5, lane-row r&15, byte k&31
#define TADDR(r, k)                                                   \
  ((size_t)((r) >> 4) * STRIP + (size_t)((k) >> 7) * 2048 +           \
   (size_t)((((k)) & 127) >> 5) * 512 + ((r) & 15) * 32 + ((k) & 31))

// -------- merged prep: blocks [0,4096) = w rows; [4096,6144) = x tiles ------
__global__ __launch_bounds__(256) void prep_all(const float* __restrict__ w,
                                                const float* __restrict__ x,
                                                uint8_t* __restrict__ w8,
                                                uint8_t* __restrict__ x8,
                                                float* __restrict__ w2,
                                                float* __restrict__ x2) {
  __shared__ uint8_t tile[64][68];
  __shared__ float red[4];
  const int bid = blockIdx.x;
  const int t = threadIdx.x;

  if (bid < M_DIM) {
    // ---- w row i: e4m3(w*64) into frag-linear tiles; exact w2 ----
    const int i = bid;
    f32x4v v =
        __builtin_nontemporal_load(((const f32x4v*)(w + (size_t)i * K_DIM)) + t);
    float ss = v.x * v.x + v.y * v.y + v.z * v.z + v.w * v.w;
    uint32_t pk = 0;
    pk = __builtin_amdgcn_cvt_pk_fp8_f32(v.x * 64.0f, v.y * 64.0f, pk, false);
    pk = __builtin_amdgcn_cvt_pk_fp8_f32(v.z * 64.0f, v.w * 64.0f, pk, true);
    *(uint32_t*)(w8 + TADDR(i, t * 4)) = pk;
#pragma unroll
    for (int off = 32; off > 0; off >>= 1) ss += __shfl_down(ss, off);
    if ((t & 63) == 0) red[t >> 6] = ss;
    __syncthreads();
    if (t == 0) w2[i] = red[0] + red[1] + red[2] + red[3];
    return;
  }

  // ---- x 64x64 tile: cast + transpose into frag-linear tiles; exact x2 ----
  const int idx = bid - M_DIM;
  const int s0 = (idx & 31) * 64;
  const int o0 = ((idx >> 5) & 15) * 64;
  const int b = idx >> 9;
  const int tr = t >> 4;
  const int tc = t & 15;
  float ss0 = 0, ss1 = 0, ss2 = 0, ss3 = 0;
#pragma unroll
  for (int p = 0; p < 4; ++p) {
    const int r = p * 16 + tr;
    f32x4v v = __builtin_nontemporal_load(
        ((const f32x4v*)(x + ((size_t)(b * K_DIM + o0 + r)) * N_DIM + s0)) + tc);
    ss0 += v.x * v.x; ss1 += v.y * v.y; ss2 += v.z * v.z; ss3 += v.w * v.w;
    uint32_t pk = 0;
    pk = __builtin_amdgcn_cvt_pk_fp8_f32(v.x, v.y, pk, false);
    pk = __builtin_amdgcn_cvt_pk_fp8_f32(v.z, v.w, pk, true);
    *(uint32_t*)&tile[r][tc * 4] = pk;
  }
  ss0 += __shfl_xor(ss0, 16); ss0 += __shfl_xor(ss0, 32);
  ss1 += __shfl_xor(ss1, 16); ss1 += __shfl_xor(ss1, 32);
  ss2 += __shfl_xor(ss2, 16); ss2 += __shfl_xor(ss2, 32);
  ss3 += __shfl_xor(ss3, 16); ss3 += __shfl_xor(ss3, 32);
  if ((t & 63) < 16) {
    float* xp = x2 + b * N_DIM + s0 + tc * 4;
    atomicAdd(xp + 0, ss0);
    atomicAdd(xp + 1, ss1);
    atomicAdd(xp + 2, ss2);
    atomicAdd(xp + 3, ss3);
  }
  __syncthreads();
#pragma unroll
  for (int p = 0; p < 4; ++p) {
    const int s = p * 16 + tr;
    const int sF = b * N_DIM + s0 + s;  // flattened row in [0, 8192)
    const int k = o0 + tc * 4;
    const int a = tc * 4;
    uint32_t o = (uint32_t)tile[a][s] | ((uint32_t)tile[a + 1][s] << 8) |
                 ((uint32_t)tile[a + 2][s] << 16) | ((uint32_t)tile[a + 3][s] << 24);
    *(uint32_t*)(x8 + TADDR(sF, k)) = o;
  }
}

// -------- GEMM (MX-fp8, unit scales, NO LDS / NO BARRIERS) ------------------
// fmt 0 = fp8 e4m3 for A and B; scales 127 = 2^0 (e8m0).
#define MFMA8(a, b, c) \
  __builtin_amdgcn_mfma_scale_f32_16x16x128_f8f6f4((a), (b), (c), 0, 0, 0, 127, 0, 127)

__global__ __launch_bounds__(256) void gemm_mse8(
    const uint8_t* __restrict__ w8, const uint8_t* __restrict__ x8,
    const float* __restrict__ w2, const float* __restrict__ x2,
    float* __restrict__ out) {
  const int tid = threadIdx.x;
  const int wid = tid >> 6;
  const int lane = tid & 63;
  const int laneR = lane & 15;
  const int g = lane >> 4;
  const int wm = wid >> 1;  // 0..1
  const int wn = wid & 1;   // 0..1

  // XCD swizzle (2048 blocks, %8==0 -> bijective); mt fastest (B-panel reuse)
  const int bid = blockIdx.x;
  const int swz = (bid & 7) * (NBLK / 8) + (bid >> 3);
  const int mt = swz & (MT - 1);
  const int nt = swz >> 5;

  // frag base pointers: strip index *16384 + lane*32; frag (mi,t) at
  // + mi*16384 + t*2048. Whole wave reads contiguous 2KB per frag.
  const uint8_t* Ab = w8 + (size_t)(mt * 8 + wm * 4) * STRIP + lane * 32;
  const uint8_t* Bb = x8 + (size_t)(nt * 8 + wn * 4) * STRIP + lane * 32;

#define LDG(base, off)                                                        \
  ({                                                                          \
    i32x4 lo_ = *(const i32x4*)((base) + (off));                              \
    i32x4 hi_ = *(const i32x4*)((base) + (off) + 16);                         \
    (i32x8){lo_[0], lo_[1], lo_[2], lo_[3], hi_[0], hi_[1], hi_[2], hi_[3]};  \
  })

  f32x4 acc[4][4] = {};
  i32x8 Af[2][4], Bf[2][4];

  // preload tile 0
#pragma unroll
  for (int i = 0; i < 4; ++i) {
    Af[0][i] = LDG(Ab, i * STRIP);
    Bf[0][i] = LDG(Bb, i * STRIP);
  }

#pragma unroll
  for (int t = 0; t < NKT; ++t) {
    const int cur = t & 1, nxt = (t + 1) & 1;  // static after full unroll
    if (t < NKT - 1) {
#pragma unroll
      for (int i = 0; i < 4; ++i) {
        Af[nxt][i] = LDG(Ab, i * STRIP + (t + 1) * 2048);
        Bf[nxt][i] = LDG(Bb, i * STRIP + (t + 1) * 2048);
      }
    }
#pragma unroll
    for (int mi = 0; mi < 4; ++mi) {
      acc[mi][0] = MFMA8(Af[cur][mi], Bf[cur][0], acc[mi][0]);
      acc[mi][1] = MFMA8(Af[cur][mi], Bf[cur][1], acc[mi][1]);
      acc[mi][2] = MFMA8(Af[cur][mi], Bf[cur][2], acc[mi][2]);
      acc[mi][3] = MFMA8(Af[cur][mi], Bf[cur][3], acc[mi][3]);
    }
  }

  // ==== epilogue: direct scatter, 64B lane-groups, L2-absorbed ====
  // out = (w2 + x2 - acc/32) / 1024   [acc = 64*wx -> 2wx = acc/32]
  const float cA = 0.03125f;
  const float inv = 1.0f / (float)K_DIM;
  const int rowb0 = mt * BM + wm * 64;  // + mi*16 + g*4 + j
  const int colf0 = nt * BN + wn * 64;  // flattened col
  const int bz = colf0 >> 11;
  const int sc0 = colf0 & (N_DIM - 1);
  float xv[4];
#pragma unroll
  for (int ni = 0; ni < 4; ++ni) xv[ni] = x2[colf0 + ni * 16 + laneR];
  float* outp = out + (size_t)bz * M_DIM * N_DIM;
#pragma unroll
  for (int mi = 0; mi < 4; ++mi) {
#pragma unroll
    for (int j = 0; j < 4; ++j) {
      const int row = rowb0 + mi * 16 + g * 4 + j;
      const float wv = w2[row];
      float* orow = outp + (size_t)row * N_DIM + sc0;
#pragma unroll
      for (int ni = 0; ni < 4; ++ni)
        orow[ni * 16 + laneR] = (wv + xv[ni] - acc[mi][ni][j] * cA) * inv;
    }
  }
#undef LDG
}

// -------- launcher -----------------------------------------------------------
extern "C" void kernel_launch(void* const* d_in, const int* in_sizes, int n_in,
                              void* d_out, int out_size, void* d_ws, size_t ws_size,
                              hipStream_t stream) {
  const float* x = (const float*)d_in[0];  // (4, 1024, 2048)
  const float* w = (const float*)d_in[1];  // (4096, 1024)
  float* out = (float*)d_out;              // (4, 4096, 2048)
  char* ws = (char*)d_ws;
  uint8_t* w8 = (uint8_t*)ws;                        // 4 MB (frag-linear)
  uint8_t* x8 = (uint8_t*)(ws + (size_t)(4 << 20));  // 8 MB (frag-linear)
  float* w2 = (float*)(ws + (size_t)(12 << 20));     // 16 KB
  float* x2 = w2 + M_DIM;                            // 32 KB

  (void)hipMemsetAsync(x2, 0, NF * sizeof(float), stream);
  prep_all<<<dim3(M_DIM + 2048), dim3(256), 0, stream>>>(w, x, w8, x8, w2, x2);
  gemm_mse8<<<dim3(NBLK), dim3(256), 0, stream>>>(w8, x8, w2, x2, out);
}

// Round 14
// 84.304 us; speedup vs baseline: 1.3451x; 1.3451x over previous
//
#include <hip/hip_runtime.h>
#include <stdint.h>

// out[b,i,s] = (||w_i||^2 - 2*sum_o w[i,o]x[b,o,s] + ||x_{b,:,s}||^2) / K
// B=4, M=4096, K=1024, N=2048 (flattened N'=8192). fp32 in/out.
// MX-fp8 cross term (mfma_scale 16x16x128, unit scales); w2/x2 exact fp32.
// R14 = R10 (best: 256x256, BK=128, 8 waves, 2x64KB dbuf, LDS-transpose
// epilogue) + 2D SUPERTILE block mapping: each XCD owns a 4mtx4nt supertile
// chain (2MB working set, fits 4MB XCD L2; B panels reused 4x per XCD).

#define M_DIM 4096
#define K_DIM 1024
#define N_DIM 2048
#define B_DIM 4
#define NF 8192  // flattened B*N

#define BM 256
#define BN 256
#define BK 128
#define NKT (K_DIM / BK)  // 8
#define MT (M_DIM / BM)   // 16
#define NT (NF / BN)      // 32
#define BUFB 65536        // 32KB A + 32KB B per buffer

typedef __attribute__((ext_vector_type(4))) int i32x4;
typedef __attribute__((ext_vector_type(8))) int i32x8;
typedef __attribute__((ext_vector_type(4))) float f32x4;
typedef __attribute__((ext_vector_type(4))) float f32x4v;

// -------- prep_w: w f32 [M][K] -> w8 = e4m3(w*64) [M][K]; w2 exact; x2=0 ----
__global__ __launch_bounds__(256) void prep_w(const float* __restrict__ w,
                                              uint8_t* __restrict__ w8,
                                              float* __restrict__ w2,
                                              float* __restrict__ x2) {
  const int i = blockIdx.x;
  const int t = threadIdx.x;
  if (i < 32) x2[i * 256 + t] = 0.0f;  // zero 8192 floats for prep_x atomics
  f32x4v v = __builtin_nontemporal_load(((const f32x4v*)(w + (size_t)i * K_DIM)) + t);
  float ss = v.x * v.x + v.y * v.y + v.z * v.z + v.w * v.w;
  uint32_t pk = 0;
  pk = __builtin_amdgcn_cvt_pk_fp8_f32(v.x * 64.0f, v.y * 64.0f, pk, false);
  pk = __builtin_amdgcn_cvt_pk_fp8_f32(v.z * 64.0f, v.w * 64.0f, pk, true);
  ((uint32_t*)(w8 + (size_t)i * K_DIM))[t] = pk;
#pragma unroll
  for (int off = 32; off > 0; off >>= 1) ss += __shfl_down(ss, off);
  __shared__ float red[4];
  if ((t & 63) == 0) red[t >> 6] = ss;
  __syncthreads();
  if (t == 0) w2[i] = red[0] + red[1] + red[2] + red[3];
}

// -------- prep_x: x f32 [B][K][N] -> x8 = e4m3(x) [B][N][K]; x2 exact -------
__global__ __launch_bounds__(256) void prep_x(const float* __restrict__ x,
                                              uint8_t* __restrict__ x8,
                                              float* __restrict__ x2) {
  __shared__ uint8_t tile[64][68];  // [o][s] fp8, pitch 68 (4-aligned)
  const int b = blockIdx.z;
  const int o0 = blockIdx.y * 64;
  const int s0 = blockIdx.x * 64;
  const int t = threadIdx.x;
  const int tr = t >> 4;
  const int tc = t & 15;
  float ss0 = 0, ss1 = 0, ss2 = 0, ss3 = 0;
#pragma unroll
  for (int p = 0; p < 4; ++p) {
    const int r = p * 16 + tr;
    f32x4v v = __builtin_nontemporal_load(
        ((const f32x4v*)(x + ((size_t)(b * K_DIM + o0 + r)) * N_DIM + s0)) + tc);
    ss0 += v.x * v.x; ss1 += v.y * v.y; ss2 += v.z * v.z; ss3 += v.w * v.w;
    uint32_t pk = 0;
    pk = __builtin_amdgcn_cvt_pk_fp8_f32(v.x, v.y, pk, false);
    pk = __builtin_amdgcn_cvt_pk_fp8_f32(v.z, v.w, pk, true);
    *(uint32_t*)&tile[r][tc * 4] = pk;
  }
  ss0 += __shfl_xor(ss0, 16); ss0 += __shfl_xor(ss0, 32);
  ss1 += __shfl_xor(ss1, 16); ss1 += __shfl_xor(ss1, 32);
  ss2 += __shfl_xor(ss2, 16); ss2 += __shfl_xor(ss2, 32);
  ss3 += __shfl_xor(ss3, 16); ss3 += __shfl_xor(ss3, 32);
  if ((t & 63) < 16) {
    float* xp = x2 + b * N_DIM + s0 + tc * 4;
    atomicAdd(xp + 0, ss0);
    atomicAdd(xp + 1, ss1);
    atomicAdd(xp + 2, ss2);
    atomicAdd(xp + 3, ss3);
  }
  __syncthreads();
#pragma unroll
  for (int p = 0; p < 4; ++p) {
    const int s = p * 16 + tr;
    const int a = tc * 4;
    uint32_t o = (uint32_t)tile[a][s] | ((uint32_t)tile[a + 1][s] << 8) |
                 ((uint32_t)tile[a + 2][s] << 16) | ((uint32_t)tile[a + 3][s] << 24);
    *(uint32_t*)(x8 + ((size_t)(b * N_DIM + s0 + s)) * K_DIM + o0 + a) = o;
  }
}

// -------- GEMM (MX-fp8, unit scales) ----------------------------------------
typedef const __attribute__((address_space(1))) uint32_t* gp_t;
typedef __attribute__((address_space(3))) uint32_t* lp_t;

__device__ __forceinline__ void gload_lds16(const void* g, const void* l) {
  __builtin_amdgcn_global_load_lds((gp_t)(uintptr_t)g,
                                   (lp_t)(uint32_t)(uintptr_t)l, 16, 0, 0);
}

// fmt 0 = fp8 e4m3 for A and B; scales 127 = 2^0 (e8m0).
#define MFMA8(a, b, c) \
  __builtin_amdgcn_mfma_scale_f32_16x16x128_f8f6f4((a), (b), (c), 0, 0, 0, 127, 0, 127)
#define FENCE() asm volatile("" ::: "memory")

__global__ __launch_bounds__(512) void gemm_mse8(
    const uint8_t* __restrict__ w8, const uint8_t* __restrict__ x8,
    const float* __restrict__ w2, const float* __restrict__ x2,
    float* __restrict__ out) {
  // LDS: 2 bufs x (A 32KB | B 32KB) = 128KB
  __shared__ __align__(32) char smem[2 * BUFB];
  const int tid = threadIdx.x;
  const int wid = tid >> 6;
  const int lane = tid & 63;
  const int laneR = lane & 15;
  const int g = lane >> 4;
  const int wm = wid >> 2;  // 0..1 (128-row half of BM=256)
  const int wn = wid & 3;   // 0..3 (64-col quarter of BN=256)

  // R14: supertile mapping. XCD = bid&7 owns nt-strip [xcd*4, xcd*4+4);
  // within it, 4 supertiles of 4mt x 4nt (2MB operand set -> L2-resident).
  const int bid = blockIdx.x;
  const int xcd = bid & 7;
  const int r = bid >> 3;   // 0..63 within XCD
  const int st = r >> 4;    // supertile 0..3 -> stm
  const int sub = r & 15;   // 4x4 within supertile, m-fastest
  const int mt = st * 4 + (sub & 3);
  const int nt = xcd * 4 + (sub >> 2);

  const uint8_t* Ag = w8 + (size_t)mt * BM * K_DIM;
  const uint8_t* Bg = x8 + (size_t)nt * BN * K_DIM;

  // staging: 8 x 16B chunks/thread (A 4, B 4); source pre-swizzled:
  // logical (row,col) -> phys row*128 + (col ^ ((row&7)<<4))
#define SRCOFF(P) ((size_t)((P) >> 7) * K_DIM + (((P) ^ ((((P) >> 7) & 7) << 4)) & 127))
  const int p0 = tid * 16;
  const uint8_t* sA0 = Ag + SRCOFF(p0);
  const uint8_t* sA1 = Ag + SRCOFF(p0 + 8192);
  const uint8_t* sA2 = Ag + SRCOFF(p0 + 16384);
  const uint8_t* sA3 = Ag + SRCOFF(p0 + 24576);
  const uint8_t* sB0 = Bg + SRCOFF(p0);
  const uint8_t* sB1 = Bg + SRCOFF(p0 + 8192);
  const uint8_t* sB2 = Bg + SRCOFF(p0 + 16384);
  const uint8_t* sB3 = Bg + SRCOFF(p0 + 24576);

#define STAGE(tt, buf)                                   \
  {                                                      \
    const int ko_ = (tt) * BK;                           \
    char* lb_ = smem + (buf) * BUFB;                     \
    gload_lds16(sA0 + ko_, lb_ + p0);                    \
    gload_lds16(sA1 + ko_, lb_ + p0 + 8192);             \
    gload_lds16(sA2 + ko_, lb_ + p0 + 16384);            \
    gload_lds16(sA3 + ko_, lb_ + p0 + 24576);            \
    gload_lds16(sB0 + ko_, lb_ + 32768 + p0);            \
    gload_lds16(sB1 + ko_, lb_ + 32768 + p0 + 8192);     \
    gload_lds16(sB2 + ko_, lb_ + 32768 + p0 + 16384);    \
    gload_lds16(sB3 + ko_, lb_ + 32768 + p0 + 24576);    \
  }

  // frag reads: lane holds k-bytes [g*32,+32) of its row; row&7 == laneR&7
  const int tail = (g << 5) ^ ((laneR & 7) << 4);
  const int offA0 = (wm * 128 + laneR) * 128 + tail;          // + mi*2048
  const int offB0 = 32768 + (wn * 64 + laneR) * 128 + tail;   // + ni*2048

#define LDF(off, bo)                                                          \
  ({                                                                          \
    i32x4 lo_ = *(const i32x4*)(smem + (bo) + (off));                         \
    i32x4 hi_ = *(const i32x4*)(smem + (bo) + ((off) ^ 16));                  \
    (i32x8){lo_[0], lo_[1], lo_[2], lo_[3], hi_[0], hi_[1], hi_[2], hi_[3]};  \
  })

  f32x4 acc[8][4] = {};

  // prologue: stage tile 0
  STAGE(0, 0);
  asm volatile("s_waitcnt vmcnt(0)" ::: "memory");
  __builtin_amdgcn_s_barrier();
  FENCE();

#pragma unroll
  for (int t = 0; t < NKT; ++t) {
    const int bo = (t & 1) * BUFB;
    // issue next-tile staging first; its buf was consumed & barrier-cleared
    if (t < NKT - 1) STAGE(t + 1, (t + 1) & 1);
    i32x8 b0 = LDF(offB0 + 0 * 2048, bo);
    i32x8 b1 = LDF(offB0 + 1 * 2048, bo);
    i32x8 b2 = LDF(offB0 + 2 * 2048, bo);
    i32x8 b3 = LDF(offB0 + 3 * 2048, bo);
    __builtin_amdgcn_s_setprio(1);
#pragma unroll
    for (int mi = 0; mi < 8; ++mi) {
      i32x8 am = LDF(offA0 + mi * 2048, bo);
      acc[mi][0] = MFMA8(am, b0, acc[mi][0]);
      acc[mi][1] = MFMA8(am, b1, acc[mi][1]);
      acc[mi][2] = MFMA8(am, b2, acc[mi][2]);
      acc[mi][3] = MFMA8(am, b3, acc[mi][3]);
    }
    __builtin_amdgcn_s_setprio(0);
    // next tile landed (compute ~2200cy covered L2 latency + BW)
    asm volatile("s_waitcnt vmcnt(0)" ::: "memory");
    // all waves' reads of buf t done before iter t+1 stages into buf t&1
    asm volatile("s_waitcnt lgkmcnt(0)" ::: "memory");
    __builtin_amdgcn_sched_barrier(0);
    __builtin_amdgcn_s_barrier();
    FENCE();
  }

  // ==== epilogue: per-wave LDS-transpose (2x 64x64 halves, 16KB/wave) ====
  // out = (w2 + x2 - acc/32) / 1024   [acc = 64*wx -> 2wx = acc/32]
  const float cA = 0.03125f;
  const float inv = 1.0f / (float)K_DIM;
  const int rowb0 = mt * BM + wm * 128;
  const int colf0 = nt * BN + wn * 64;  // flattened col in [0, 8192)
  const int bz = colf0 >> 11;
  const int sc0 = colf0 & (N_DIM - 1);
  float xv[4];
#pragma unroll
  for (int ni = 0; ni < 4; ++ni) xv[ni] = x2[colf0 + ni * 16 + laneR];
  float* lds_f = (float*)smem + wid * 4096;  // 16KB per wave, private
  float* outp = out + (size_t)bz * M_DIM * N_DIM;

#pragma unroll
  for (int miH = 0; miH < 2; ++miH) {
#pragma unroll
    for (int mi4 = 0; mi4 < 4; ++mi4) {
      const int mi = miH * 4 + mi4;
#pragma unroll
      for (int j = 0; j < 4; ++j) {
        const int r2 = mi4 * 16 + g * 4 + j;  // local 0..63
        const float wv = w2[rowb0 + miH * 64 + r2];
#pragma unroll
        for (int ni = 0; ni < 4; ++ni) {
          const int c = ni * 16 + laneR;
          lds_f[r2 * 64 + (c ^ ((r2 & 7) << 2))] =
              (wv + xv[ni] - acc[mi][ni][j] * cA) * inv;
        }
      }
    }
#pragma unroll
    for (int k = 0; k < 16; ++k) {
      const int r2 = k * 4 + (lane >> 4);
      const int c0 = laneR * 4;
      f32x4 v = *(const f32x4*)&lds_f[r2 * 64 + (c0 ^ ((r2 & 7) << 2))];
      *(f32x4*)(outp + (size_t)(rowb0 + miH * 64 + r2) * N_DIM + sc0 + c0) = v;
    }
    asm volatile("s_waitcnt lgkmcnt(0)" ::: "memory");
  }
#undef STAGE
#undef LDF
#undef SRCOFF
}

// -------- launcher -----------------------------------------------------------
extern "C" void kernel_launch(void* const* d_in, const int* in_sizes, int n_in,
                              void* d_out, int out_size, void* d_ws, size_t ws_size,
                              hipStream_t stream) {
  const float* x = (const float*)d_in[0];  // (4, 1024, 2048)
  const float* w = (const float*)d_in[1];  // (4096, 1024)
  float* out = (float*)d_out;              // (4, 4096, 2048)
  char* ws = (char*)d_ws;
  uint8_t* w8 = (uint8_t*)ws;                        // 4 MB
  uint8_t* x8 = (uint8_t*)(ws + (size_t)(4 << 20));  // 8 MB
  float* w2 = (float*)(ws + (size_t)(12 << 20));     // 16 KB
  float* x2 = w2 + M_DIM;                            // 32 KB

  prep_w<<<dim3(M_DIM), dim3(256), 0, stream>>>(w, w8, w2, x2);
  prep_x<<<dim3(N_DIM / 64, K_DIM / 64, B_DIM), dim3(256), 0, stream>>>(x, x8, x2);
  gemm_mse8<<<dim3(MT * NT), dim3(512), 0, stream>>>(w8, x8, w2, x2, out);
}